// Round 4
// baseline (380.782 us; speedup 1.0000x reference)
//
#include <hip/hip_runtime.h>

// BootstrapLoss: mean of the top-20% per-pixel (channel-mean) squared errors.
// input/target: [64, 3, 256, 256] fp32. N_pix = 4194304; k = 838861 largest.
//
// Single-pass histogram selection on the float bit pattern (non-negative
// floats order like their uint32 bit patterns). 4096 bins = sign+exp+4
// mantissa bits (bits>>19), per-bin COUNT+SUM; threshold bin uses bin avg
// (measured absmax 0.0 vs tolerance 448).
//
// R3 lesson: compiler re-serializes multi-iteration load batches (VGPR stuck
// at 44). Fix: ONE vec4 per thread -> 6 independent float4 loads feeding one
// fused expression, exactly one stall round; 4096 blocks for TLP (5 resident
// blocks/CU at 32KB LDS). Finalize fused via threadfence+ticket last-block
// pattern (agent-scope atomic loads for cross-XCD visibility).

#define NPIX   (64 * 256 * 256)   // 4194304
#define NV4    (NPIX / 4)         // 1048576
#define HW     65536
#define CHW    196608
#define KTAIL  838861             // 4194304 - int(0.8 * 4194304)
#define NBIN   4096
#define NBLK   4096               // NBLK * 256 == NV4

__device__ inline float sqf(float x) { return x * x; }

__global__ __launch_bounds__(256)
void k_main(const float4* __restrict__ in, const float4* __restrict__ tg,
            unsigned* __restrict__ gcnt, double* __restrict__ gsum,
            unsigned* __restrict__ ticket, float* __restrict__ out) {
  __shared__ unsigned h[NBIN];                 // 16 KB
  __shared__ double fs_d[NBIN / 2];            // 16 KB (double-aligned; aliased as float[NBIN])
  float* fs = (float*)fs_d;

  // ---- issue all 6 independent float4 loads first (one stall round/thread)
  const int i  = blockIdx.x * 256 + threadIdx.x;   // vec4 index
  const int p  = i << 2;                           // pixel index
  const int bb = p >> 16;                          // batch (p / HW)
  const int hw = p & (HW - 1);
  const int base4 = (bb * CHW + hw) >> 2;
  float4 a0 = in[base4];
  float4 a1 = in[base4 + HW / 4];
  float4 a2 = in[base4 + HW / 2];
  float4 t0 = tg[base4];
  float4 t1 = tg[base4 + HW / 4];
  float4 t2 = tg[base4 + HW / 2];

  // LDS init overlaps load latency
  for (int j = threadIdx.x; j < NBIN; j += 256) { h[j] = 0u; fs[j] = 0.0f; }
  __syncthreads();

  const float S = 65025.0f / 3.0f;   // (255^2)/3
  float vv[4];
  vv[0] = (sqf(a0.x - t0.x) + sqf(a1.x - t1.x) + sqf(a2.x - t2.x)) * S;
  vv[1] = (sqf(a0.y - t0.y) + sqf(a1.y - t1.y) + sqf(a2.y - t2.y)) * S;
  vv[2] = (sqf(a0.z - t0.z) + sqf(a1.z - t1.z) + sqf(a2.z - t2.z)) * S;
  vv[3] = (sqf(a0.w - t0.w) + sqf(a1.w - t1.w) + sqf(a2.w - t2.w)) * S;
#pragma unroll
  for (int c = 0; c < 4; ++c) {
    unsigned bin = __float_as_uint(vv[c]) >> 19;
    atomicAdd(&h[bin], 1u);
    atomicAdd(&fs[bin], vv[c]);
  }
  __syncthreads();

  // ---- flush block-private histogram to global accumulators
  for (int j = threadIdx.x; j < NBIN; j += 256) {
    unsigned c = h[j];
    if (c) {
      atomicAdd(&gcnt[j], c);
      atomicAdd(&gsum[j], (double)fs[j]);
    }
  }

  // ---- last-block finalize (canonical threadfence + ticket pattern)
  __shared__ int is_last;
  __threadfence();
  __syncthreads();
  if (threadIdx.x == 0) {
    unsigned done = atomicAdd(ticket, 1u);
    is_last = (done == (unsigned)(NBLK - 1)) ? 1 : 0;
  }
  __syncthreads();
  if (!is_last) return;

  // reuse LDS: chunk totals (h -> ccnt, fs_d -> csum)
  unsigned* ccnt = h;
  double*   csum = fs_d;
  __shared__ int   sel_chunk;
  __shared__ long  cum_base;
  __shared__ double above_base;

  const int t = threadIdx.x;
  unsigned cnt[16];
  double   sm[16];
  unsigned lc = 0u;
  double   ls = 0.0;
#pragma unroll
  for (int j = 0; j < 16; ++j) {
    int idx = t * 16 + j;
    cnt[j] = __hip_atomic_load(&gcnt[idx], __ATOMIC_RELAXED, __HIP_MEMORY_SCOPE_AGENT);
    sm[j]  = __hip_atomic_load(&gsum[idx], __ATOMIC_RELAXED, __HIP_MEMORY_SCOPE_AGENT);
    lc += cnt[j];
    ls += sm[j];
  }
  __syncthreads();   // LDS reuse: everyone past the histogram phase
  ccnt[t] = lc;
  csum[t] = ls;
  __syncthreads();

  if (t == 0) {
    long cum = 0;
    double ab = 0.0;
    int c = 255;
    for (; c > 0; --c) {
      if (cum + (long)ccnt[c] >= (long)KTAIL) break;
      cum += ccnt[c];
      ab  += csum[c];
    }
    sel_chunk  = c;
    cum_base   = cum;
    above_base = ab;
  }
  __syncthreads();

  if (t == sel_chunk) {
    long cum = cum_base;
    double ab = above_base;
    int bsel = -1;
    // fully-unrolled static-index scan (keeps cnt/sm in registers, rule #20)
#pragma unroll
    for (int j = 15; j >= 0; --j) {
      if (bsel < 0) {
        long ncum = cum + (long)cnt[j];
        if (ncum >= (long)KTAIL || j == 0) {
          bsel = j;
        } else {
          cum = ncum;
          ab += sm[j];
        }
      }
    }
    long r = (long)KTAIL - cum;
    double avg = cnt[bsel] ? sm[bsel] / (double)cnt[bsel] : 0.0;
    out[0] = (float)((ab + (double)r * avg) / (double)KTAIL);
  }
}

extern "C" void kernel_launch(void* const* d_in, const int* in_sizes, int n_in,
                              void* d_out, int out_size, void* d_ws, size_t ws_size,
                              hipStream_t stream) {
  (void)in_sizes; (void)n_in; (void)out_size; (void)ws_size;
  const float4* in = (const float4*)d_in[0];
  const float4* tg = (const float4*)d_in[1];
  float* out = (float*)d_out;
  char* ws = (char*)d_ws;

  unsigned* gcnt   = (unsigned*)ws;                          // 16 KB
  double*   gsum   = (double*)(ws + NBIN * 4);               // 32 KB
  unsigned* ticket = (unsigned*)(ws + NBIN * 4 + NBIN * 8);  // 4 B

  // zero accumulators + ticket every call (graph replays reuse ws)
  hipMemsetAsync(gcnt, 0, NBIN * 4 + NBIN * 8 + 16, stream);

  k_main<<<dim3(NBLK), dim3(256), 0, stream>>>(in, tg, gcnt, gsum, ticket, out);
}

// Round 5
// 188.649 us; speedup vs baseline: 2.0185x; 2.0185x over previous
//
#include <hip/hip_runtime.h>

// BootstrapLoss: mean of the top-20% per-pixel (channel-mean) squared errors.
// input/target: [64, 3, 256, 256] fp32. N_pix = 4194304; k = 838861 largest.
//
// Single-pass histogram selection on the float bit pattern (non-negative
// floats order like their uint32 bit patterns). 4096 bins = sign+exp+4
// mantissa bits (bits>>19), per-bin COUNT+SUM; threshold bin uses bin avg
// (measured absmax 0.0 vs tolerance 448).
//
// R4 lesson: 4096 small blocks -> global-flush atomic contention on ~150 hot
// bins (4096 serialized double RMWs per address) = 489us. Amortize: few
// blocks, many values each. R2 lesson: 1024 blocks = only 16 waves/CU, loads
// latency-bound at 2.4 TB/s. Fix: 512 blocks x 1024 threads (2 blocks/CU at
// 32KB LDS = 32 waves/CU = 100% occupancy), 2 vec4/thread.

#define NPIX   (64 * 256 * 256)   // 4194304
#define NV4    (NPIX / 4)         // 1048576
#define HW     65536
#define CHW    196608
#define KTAIL  838861             // 4194304 - int(0.8 * 4194304)
#define NBIN   4096
#define NBLK   512
#define NTHR   1024
#define VITER  2                  // NBLK * NTHR * VITER == NV4

__device__ inline float sqf(float x) { return x * x; }

__global__ __launch_bounds__(NTHR, 8)   // 8 waves/EU -> 2 blocks/CU, VGPR cap 64
void k_main(const float4* __restrict__ in, const float4* __restrict__ tg,
            unsigned* __restrict__ gcnt, double* __restrict__ gsum,
            unsigned* __restrict__ ticket, float* __restrict__ out) {
  __shared__ unsigned h[NBIN];                 // 16 KB
  __shared__ double fs_d[NBIN / 2];            // 16 KB (aliased as float[NBIN])
  float* fs = (float*)fs_d;

  for (int j = threadIdx.x; j < NBIN; j += NTHR) { h[j] = 0u; fs[j] = 0.0f; }
  __syncthreads();

  const float S = 65025.0f / 3.0f;   // (255^2)/3
#pragma unroll
  for (int u = 0; u < VITER; ++u) {
    const int i  = (blockIdx.x * VITER + u) * NTHR + threadIdx.x;  // vec4 idx
    const int p  = i << 2;
    const int bb = p >> 16;           // batch (p / HW)
    const int hw = p & (HW - 1);
    const int base4 = (bb * CHW + hw) >> 2;
    float4 a0 = in[base4];
    float4 a1 = in[base4 + HW / 4];
    float4 a2 = in[base4 + HW / 2];
    float4 t0 = tg[base4];
    float4 t1 = tg[base4 + HW / 4];
    float4 t2 = tg[base4 + HW / 2];
    float vv[4];
    vv[0] = (sqf(a0.x - t0.x) + sqf(a1.x - t1.x) + sqf(a2.x - t2.x)) * S;
    vv[1] = (sqf(a0.y - t0.y) + sqf(a1.y - t1.y) + sqf(a2.y - t2.y)) * S;
    vv[2] = (sqf(a0.z - t0.z) + sqf(a1.z - t1.z) + sqf(a2.z - t2.z)) * S;
    vv[3] = (sqf(a0.w - t0.w) + sqf(a1.w - t1.w) + sqf(a2.w - t2.w)) * S;
#pragma unroll
    for (int c = 0; c < 4; ++c) {
      unsigned bin = __float_as_uint(vv[c]) >> 19;
      atomicAdd(&h[bin], 1u);
      atomicAdd(&fs[bin], vv[c]);
    }
  }
  __syncthreads();

  // ---- flush block-private histogram to global accumulators
  for (int j = threadIdx.x; j < NBIN; j += NTHR) {
    unsigned c = h[j];
    if (c) {
      atomicAdd(&gcnt[j], c);
      atomicAdd(&gsum[j], (double)fs[j]);
    }
  }

  // ---- last-block finalize (threadfence + ticket)
  __shared__ int is_last;
  __threadfence();
  __syncthreads();
  if (threadIdx.x == 0) {
    unsigned done = atomicAdd(ticket, 1u);
    is_last = (done == (unsigned)(NBLK - 1)) ? 1 : 0;
  }
  __syncthreads();
  if (!is_last) return;

  // reuse LDS: chunk totals (h -> ccnt, fs_d -> csum); only threads 0..255
  unsigned* ccnt = h;
  double*   csum = fs_d;
  __shared__ int    sel_chunk;
  __shared__ long   cum_base;
  __shared__ double above_base;

  const int t = threadIdx.x;
  unsigned cnt[16];
  double   sm[16];
  if (t < 256) {
    unsigned lc = 0u;
    double   ls = 0.0;
#pragma unroll
    for (int j = 0; j < 16; ++j) {
      int idx = t * 16 + j;
      cnt[j] = __hip_atomic_load(&gcnt[idx], __ATOMIC_RELAXED, __HIP_MEMORY_SCOPE_AGENT);
      sm[j]  = __hip_atomic_load(&gsum[idx], __ATOMIC_RELAXED, __HIP_MEMORY_SCOPE_AGENT);
      lc += cnt[j];
      ls += sm[j];
    }
    __syncthreads();   // LDS reuse barrier (within t<256? need all) -- see below
    ccnt[t] = lc;
    csum[t] = ls;
  } else {
    __syncthreads();
  }
  __syncthreads();

  if (t == 0) {
    long cum = 0;
    double ab = 0.0;
    int c = 255;
    for (; c > 0; --c) {
      if (cum + (long)ccnt[c] >= (long)KTAIL) break;
      cum += ccnt[c];
      ab  += csum[c];
    }
    sel_chunk  = c;
    cum_base   = cum;
    above_base = ab;
  }
  __syncthreads();

  if (t == sel_chunk) {   // t < 256 by construction
    long cum = cum_base;
    double ab = above_base;
    int bsel = -1;
#pragma unroll
    for (int j = 15; j >= 0; --j) {
      if (bsel < 0) {
        long ncum = cum + (long)cnt[j];
        if (ncum >= (long)KTAIL || j == 0) {
          bsel = j;
        } else {
          cum = ncum;
          ab += sm[j];
        }
      }
    }
    long r = (long)KTAIL - cum;
    double avg = cnt[bsel] ? sm[bsel] / (double)cnt[bsel] : 0.0;
    out[0] = (float)((ab + (double)r * avg) / (double)KTAIL);
  }
}

extern "C" void kernel_launch(void* const* d_in, const int* in_sizes, int n_in,
                              void* d_out, int out_size, void* d_ws, size_t ws_size,
                              hipStream_t stream) {
  (void)in_sizes; (void)n_in; (void)out_size; (void)ws_size;
  const float4* in = (const float4*)d_in[0];
  const float4* tg = (const float4*)d_in[1];
  float* out = (float*)d_out;
  char* ws = (char*)d_ws;

  unsigned* gcnt   = (unsigned*)ws;                          // 16 KB
  double*   gsum   = (double*)(ws + NBIN * 4);               // 32 KB
  unsigned* ticket = (unsigned*)(ws + NBIN * 4 + NBIN * 8);  // 4 B

  // zero accumulators + ticket every call (graph replays reuse ws)
  hipMemsetAsync(gcnt, 0, NBIN * 4 + NBIN * 8 + 16, stream);

  k_main<<<dim3(NBLK), dim3(NTHR), 0, stream>>>(in, tg, gcnt, gsum, ticket, out);
}

// Round 6
// 53.945 us; speedup vs baseline: 7.0587x; 3.4970x over previous
//
#include <hip/hip_runtime.h>

// BootstrapLoss: mean of the top-20% per-pixel (channel-mean) squared errors.
// input/target: [64, 3, 256, 256] fp32. N_pix = 4194304; k = 838861 largest.
//
// Single-pass histogram selection on the float bit pattern (non-negative
// floats order like their uint32 bit patterns). 4096 bins = sign+exp+4
// mantissa bits (bits>>19), per-bin COUNT+SUM in block-private LDS, flushed
// once per block to global; separate tiny finalize kernel scans bins from
// the top and uses the threshold bin's average (measured absmax 0.0).
//
// R4/R5 lesson: fused last-block finalize (__threadfence + ticket) poisons
// the whole kernel (agent-scope fence -> L2 writeback/inv interleaved with
// streaming reads): 42us -> 220-489us across two different grid shapes.
// Two-kernel structure is the fast one. This round: R2 skeleton, occupancy
// 16 -> 32 waves/CU (512-thread blocks, 4 blocks/CU at 32KB LDS).

#define NPIX   (64 * 256 * 256)   // 4194304
#define NV4    (NPIX / 4)         // 1048576
#define HW     65536
#define CHW    196608
#define KTAIL  838861             // 4194304 - int(0.8 * 4194304)
#define NBIN   4096
#define NBLK   1024
#define NTHR   512
#define VITER  2                  // NBLK * NTHR * VITER == NV4

__device__ inline float sqf(float x) { return x * x; }

__global__ __launch_bounds__(NTHR)
void k_main(const float4* __restrict__ in, const float4* __restrict__ tg,
            unsigned* __restrict__ gcnt, double* __restrict__ gsum) {
  __shared__ unsigned h[NBIN];       // 16 KB
  __shared__ float    fs[NBIN];      // 16 KB
  for (int j = threadIdx.x; j < NBIN; j += NTHR) { h[j] = 0u; fs[j] = 0.0f; }
  __syncthreads();

  const float S = 65025.0f / 3.0f;   // (255^2)/3
#pragma unroll
  for (int u = 0; u < VITER; ++u) {
    const int i  = (blockIdx.x * VITER + u) * NTHR + threadIdx.x;  // vec4 idx
    const int p  = i << 2;
    const int bb = p >> 16;           // batch (p / HW)
    const int hw = p & (HW - 1);
    const int base4 = (bb * CHW + hw) >> 2;
    float4 a0 = in[base4];
    float4 a1 = in[base4 + HW / 4];
    float4 a2 = in[base4 + HW / 2];
    float4 t0 = tg[base4];
    float4 t1 = tg[base4 + HW / 4];
    float4 t2 = tg[base4 + HW / 2];
    float vv[4];
    vv[0] = (sqf(a0.x - t0.x) + sqf(a1.x - t1.x) + sqf(a2.x - t2.x)) * S;
    vv[1] = (sqf(a0.y - t0.y) + sqf(a1.y - t1.y) + sqf(a2.y - t2.y)) * S;
    vv[2] = (sqf(a0.z - t0.z) + sqf(a1.z - t1.z) + sqf(a2.z - t2.z)) * S;
    vv[3] = (sqf(a0.w - t0.w) + sqf(a1.w - t1.w) + sqf(a2.w - t2.w)) * S;
#pragma unroll
    for (int c = 0; c < 4; ++c) {
      unsigned bin = __float_as_uint(vv[c]) >> 19;
      atomicAdd(&h[bin], 1u);
      atomicAdd(&fs[bin], vv[c]);
    }
  }
  __syncthreads();

  // flush block-private histogram to global accumulators (one atomic pair
  // per nonzero bin per block; 1024 blocks of contention = known-good)
  for (int j = threadIdx.x; j < NBIN; j += NTHR) {
    unsigned c = h[j];
    if (c) {
      atomicAdd(&gcnt[j], c);
      atomicAdd(&gsum[j], (double)fs[j]);
    }
  }
}

__global__ void k_final(const unsigned* __restrict__ gcnt,
                        const double* __restrict__ gsum,
                        float* __restrict__ out) {
  __shared__ unsigned h[NBIN];
  __shared__ double s[NBIN];
  __shared__ unsigned cc[256];
  __shared__ double cs[256];
  const int t = threadIdx.x;
  unsigned lc = 0u;
  double ls = 0.0;
  for (int j = 0; j < 16; ++j) {
    int idx = t * 16 + j;
    unsigned c = gcnt[idx];
    double d = gsum[idx];
    h[idx] = c;
    s[idx] = d;
    lc += c;
    ls += d;
  }
  cc[t] = lc;
  cs[t] = ls;
  __syncthreads();
  if (t == 0) {
    long cum = 0;
    double above = 0.0;
    int chunk = 255;
    for (; chunk > 0; --chunk) {
      if (cum + (long)cc[chunk] >= (long)KTAIL) break;
      cum += cc[chunk];
      above += cs[chunk];
    }
    int b = chunk * 16 + 15;
    for (; b > 0; --b) {
      unsigned c = h[b];
      if (cum + (long)c >= (long)KTAIL) break;
      cum += c;
      above += s[b];
    }
    long r = (long)KTAIL - cum;
    unsigned cb = h[b];
    double avg = cb ? s[b] / (double)cb : 0.0;
    out[0] = (float)((above + (double)r * avg) / (double)KTAIL);
  }
}

extern "C" void kernel_launch(void* const* d_in, const int* in_sizes, int n_in,
                              void* d_out, int out_size, void* d_ws, size_t ws_size,
                              hipStream_t stream) {
  (void)in_sizes; (void)n_in; (void)out_size; (void)ws_size;
  const float4* in = (const float4*)d_in[0];
  const float4* tg = (const float4*)d_in[1];
  float* out = (float*)d_out;
  char* ws = (char*)d_ws;

  unsigned* gcnt = (unsigned*)ws;                  // 16 KB
  double*   gsum = (double*)(ws + NBIN * 4);       // 32 KB

  // zero accumulators every call (graph replays reuse ws)
  hipMemsetAsync(gcnt, 0, NBIN * 4 + NBIN * 8, stream);

  k_main<<<dim3(NBLK), dim3(NTHR), 0, stream>>>(in, tg, gcnt, gsum);
  k_final<<<1, 256, 0, stream>>>(gcnt, gsum, out);
}

// Round 7
// 48.394 us; speedup vs baseline: 7.8683x; 1.1147x over previous
//
#include <hip/hip_runtime.h>

// BootstrapLoss: mean of the top-20% per-pixel (channel-mean) squared errors.
// input/target: [64, 3, 256, 256] fp32. N_pix = 4194304; k = 838861 largest.
//
// Single-pass histogram selection on the float bit pattern (non-negative
// floats order like their uint32 bit patterns). 4096 bins = sign+exp+4
// mantissa bits (bits>>19), per-bin COUNT+SUM in block-private LDS, flushed
// once per block to global; tiny finalize kernel scans from the top and uses
// the threshold bin's average (measured absmax 0.0 vs tolerance 448).
//
// Perf model (R6): k_main reads 402 MB once at ~9.5 TB/s effective (mostly
// L3-resident; FETCH_SIZE ~49 MB) -> ~42 us = Infinity-Cache path roofline.
// Occupancy doubling (R6) changed nothing; latency/VALU/LDS-atomic all ruled
// out by arithmetic. R4/R5 lesson: NO per-block __threadfence finalize (L2
// writeback storms, 5-10x regression). This round: parallel k_final scan.

#define NPIX   (64 * 256 * 256)   // 4194304
#define NV4    (NPIX / 4)         // 1048576
#define HW     65536
#define CHW    196608
#define KTAIL  838861             // 4194304 - int(0.8 * 4194304)
#define NBIN   4096
#define NBLK   1024
#define NTHR   512
#define VITER  2                  // NBLK * NTHR * VITER == NV4

__device__ inline float sqf(float x) { return x * x; }

__global__ __launch_bounds__(NTHR)
void k_main(const float4* __restrict__ in, const float4* __restrict__ tg,
            unsigned* __restrict__ gcnt, double* __restrict__ gsum) {
  __shared__ unsigned h[NBIN];       // 16 KB
  __shared__ float    fs[NBIN];      // 16 KB
  for (int j = threadIdx.x; j < NBIN; j += NTHR) { h[j] = 0u; fs[j] = 0.0f; }
  __syncthreads();

  const float S = 65025.0f / 3.0f;   // (255^2)/3
#pragma unroll
  for (int u = 0; u < VITER; ++u) {
    const int i  = (blockIdx.x * VITER + u) * NTHR + threadIdx.x;  // vec4 idx
    const int p  = i << 2;
    const int bb = p >> 16;           // batch (p / HW)
    const int hw = p & (HW - 1);
    const int base4 = (bb * CHW + hw) >> 2;
    float4 a0 = in[base4];
    float4 a1 = in[base4 + HW / 4];
    float4 a2 = in[base4 + HW / 2];
    float4 t0 = tg[base4];
    float4 t1 = tg[base4 + HW / 4];
    float4 t2 = tg[base4 + HW / 2];
    float vv[4];
    vv[0] = (sqf(a0.x - t0.x) + sqf(a1.x - t1.x) + sqf(a2.x - t2.x)) * S;
    vv[1] = (sqf(a0.y - t0.y) + sqf(a1.y - t1.y) + sqf(a2.y - t2.y)) * S;
    vv[2] = (sqf(a0.z - t0.z) + sqf(a1.z - t1.z) + sqf(a2.z - t2.z)) * S;
    vv[3] = (sqf(a0.w - t0.w) + sqf(a1.w - t1.w) + sqf(a2.w - t2.w)) * S;
#pragma unroll
    for (int c = 0; c < 4; ++c) {
      unsigned bin = __float_as_uint(vv[c]) >> 19;
      atomicAdd(&h[bin], 1u);
      atomicAdd(&fs[bin], vv[c]);
    }
  }
  __syncthreads();

  // flush block-private histogram to global accumulators
  for (int j = threadIdx.x; j < NBIN; j += NTHR) {
    unsigned c = h[j];
    if (c) {
      atomicAdd(&gcnt[j], c);
      atomicAdd(&gsum[j], (double)fs[j]);
    }
  }
}

// 256 threads; t owns bins [16t, 16t+16). Hillis-Steele suffix scan over the
// 256 chunk totals (count + sum), then the unique chunk containing the k-th
// largest resolves its 16 bins from registers (static-index unrolled).
__global__ __launch_bounds__(256)
void k_final(const unsigned* __restrict__ gcnt,
             const double* __restrict__ gsum,
             float* __restrict__ out) {
  __shared__ unsigned cumC[256];
  __shared__ double   cumS[256];
  const int t = threadIdx.x;

  unsigned cnt[16];
  double   sm[16];
  unsigned lc = 0u;
  double   ls = 0.0;
#pragma unroll
  for (int j = 0; j < 16; ++j) {
    int idx = t * 16 + j;
    cnt[j] = gcnt[idx];
    sm[j]  = gsum[idx];
    lc += cnt[j];
    ls += sm[j];
  }
  cumC[t] = lc;
  cumS[t] = ls;
  __syncthreads();

  // inclusive suffix scan: cumC[t] = sum_{t' >= t} chunk_count(t')
#pragma unroll
  for (int off = 1; off < 256; off <<= 1) {
    unsigned c = (t + off < 256) ? cumC[t + off] : 0u;
    double   s = (t + off < 256) ? cumS[t + off] : 0.0;
    __syncthreads();
    cumC[t] += c;
    cumS[t] += s;
    __syncthreads();
  }

  const unsigned above  = cumC[t] - lc;   // count in chunks strictly above t
  // exactly one t satisfies: above < KTAIL <= cumC[t]
  if (above < (unsigned)KTAIL && cumC[t] >= (unsigned)KTAIL) {
    long   cum = (long)above;
    double ab  = cumS[t] - ls;            // sum of values in chunks above
    int bsel = -1;
#pragma unroll
    for (int j = 15; j >= 0; --j) {
      if (bsel < 0) {
        if (cum + (long)cnt[j] >= (long)KTAIL || j == 0) {
          bsel = j;
        } else {
          cum += (long)cnt[j];
          ab  += sm[j];
        }
      }
    }
    long r = (long)KTAIL - cum;
    double avg = cnt[bsel] ? sm[bsel] / (double)cnt[bsel] : 0.0;
    out[0] = (float)((ab + (double)r * avg) / (double)KTAIL);
  }
}

extern "C" void kernel_launch(void* const* d_in, const int* in_sizes, int n_in,
                              void* d_out, int out_size, void* d_ws, size_t ws_size,
                              hipStream_t stream) {
  (void)in_sizes; (void)n_in; (void)out_size; (void)ws_size;
  const float4* in = (const float4*)d_in[0];
  const float4* tg = (const float4*)d_in[1];
  float* out = (float*)d_out;
  char* ws = (char*)d_ws;

  unsigned* gcnt = (unsigned*)ws;                  // 16 KB
  double*   gsum = (double*)(ws + NBIN * 4);       // 32 KB

  // zero accumulators every call (graph replays reuse ws)
  hipMemsetAsync(gcnt, 0, NBIN * 4 + NBIN * 8, stream);

  k_main<<<dim3(NBLK), dim3(NTHR), 0, stream>>>(in, tg, gcnt, gsum);
  k_final<<<1, 256, 0, stream>>>(gcnt, gsum, out);
}

// Round 8
// 43.171 us; speedup vs baseline: 8.8204x; 1.1210x over previous
//
#include <hip/hip_runtime.h>

// BootstrapLoss: mean of the top-20% per-pixel (channel-mean) squared errors.
// input/target: [64, 3, 256, 256] fp32. N_pix = 4194304; k = 838861 largest.
//
// Single-pass histogram selection on the float bit pattern (non-negative
// floats order like their uint32 bit patterns). 4096 bins = sign+exp+4
// mantissa bits (bits>>19). Per-bin (count,sum) packed into ONE 64-bit LDS
// atomic per value: [63:48] count, [47:0] sum in 1/1024 fixed point
// (count<=4096 fits 16b; sum <= 4096*65025*1024 = 2.7e11 < 2^48; quant
// error <= 5e-4 vs tolerance 448). Halves LDS atomic ops vs R7 and spreads
// 16-consecutive hot bins across all 32 banks (u64 spans 2 banks).
//
// R4/R5 lesson: NO per-block __threadfence finalize (L2 writeback storms).
// R6 lesson: occupancy-insensitive at 41us (9.8 TB/s effective, L3-resident)
// -> this round isolates the LDS-atomic hypothesis; if unchanged, k_main is
// at the Infinity-Cache read-path roofline.

#define NPIX   (64 * 256 * 256)   // 4194304
#define NV4    (NPIX / 4)         // 1048576
#define HW     65536
#define CHW    196608
#define KTAIL  838861             // 4194304 - int(0.8 * 4194304)
#define NBIN   4096
#define NBLK   1024
#define NTHR   512
#define VITER  2                  // NBLK * NTHR * VITER == NV4

#define FIXSHIFT 10               // sum fixed point = value * 1024
#define CNTSHIFT 48
#define SUMMASK  ((1ull << CNTSHIFT) - 1ull)

__device__ inline float sqf(float x) { return x * x; }

__global__ __launch_bounds__(NTHR)
void k_main(const float4* __restrict__ in, const float4* __restrict__ tg,
            unsigned* __restrict__ gcnt, double* __restrict__ gsum) {
  __shared__ unsigned long long h[NBIN];   // 32 KB
  for (int j = threadIdx.x; j < NBIN; j += NTHR) h[j] = 0ull;
  __syncthreads();

  const float S = 65025.0f / 3.0f;   // (255^2)/3
#pragma unroll
  for (int u = 0; u < VITER; ++u) {
    const int i  = (blockIdx.x * VITER + u) * NTHR + threadIdx.x;  // vec4 idx
    const int p  = i << 2;
    const int bb = p >> 16;           // batch (p / HW)
    const int hw = p & (HW - 1);
    const int base4 = (bb * CHW + hw) >> 2;
    float4 a0 = in[base4];
    float4 a1 = in[base4 + HW / 4];
    float4 a2 = in[base4 + HW / 2];
    float4 t0 = tg[base4];
    float4 t1 = tg[base4 + HW / 4];
    float4 t2 = tg[base4 + HW / 2];
    float vv[4];
    vv[0] = (sqf(a0.x - t0.x) + sqf(a1.x - t1.x) + sqf(a2.x - t2.x)) * S;
    vv[1] = (sqf(a0.y - t0.y) + sqf(a1.y - t1.y) + sqf(a2.y - t2.y)) * S;
    vv[2] = (sqf(a0.z - t0.z) + sqf(a1.z - t1.z) + sqf(a2.z - t2.z)) * S;
    vv[3] = (sqf(a0.w - t0.w) + sqf(a1.w - t1.w) + sqf(a2.w - t2.w)) * S;
#pragma unroll
    for (int c = 0; c < 4; ++c) {
      unsigned bin = __float_as_uint(vv[c]) >> 19;
      unsigned long long q =
          (unsigned long long)(vv[c] * (float)(1 << FIXSHIFT) + 0.5f);
      atomicAdd(&h[bin], (1ull << CNTSHIFT) | q);
    }
  }
  __syncthreads();

  // flush block-private histogram to global accumulators
  for (int j = threadIdx.x; j < NBIN; j += NTHR) {
    unsigned long long v = h[j];
    if (v) {
      unsigned c = (unsigned)(v >> CNTSHIFT);
      double s = (double)(v & SUMMASK) * (1.0 / (double)(1 << FIXSHIFT));
      atomicAdd(&gcnt[j], c);
      atomicAdd(&gsum[j], s);
    }
  }
}

// 256 threads; t owns bins [16t, 16t+16). Hillis-Steele suffix scan over the
// 256 chunk totals (count + sum), then the unique chunk containing the k-th
// largest resolves its 16 bins from registers (static-index unrolled).
__global__ __launch_bounds__(256)
void k_final(const unsigned* __restrict__ gcnt,
             const double* __restrict__ gsum,
             float* __restrict__ out) {
  __shared__ unsigned cumC[256];
  __shared__ double   cumS[256];
  const int t = threadIdx.x;

  unsigned cnt[16];
  double   sm[16];
  unsigned lc = 0u;
  double   ls = 0.0;
#pragma unroll
  for (int j = 0; j < 16; ++j) {
    int idx = t * 16 + j;
    cnt[j] = gcnt[idx];
    sm[j]  = gsum[idx];
    lc += cnt[j];
    ls += sm[j];
  }
  cumC[t] = lc;
  cumS[t] = ls;
  __syncthreads();

  // inclusive suffix scan: cumC[t] = sum_{t' >= t} chunk_count(t')
#pragma unroll
  for (int off = 1; off < 256; off <<= 1) {
    unsigned c = (t + off < 256) ? cumC[t + off] : 0u;
    double   s = (t + off < 256) ? cumS[t + off] : 0.0;
    __syncthreads();
    cumC[t] += c;
    cumS[t] += s;
    __syncthreads();
  }

  const unsigned above = cumC[t] - lc;   // count in chunks strictly above t
  if (above < (unsigned)KTAIL && cumC[t] >= (unsigned)KTAIL) {
    long   cum = (long)above;
    double ab  = cumS[t] - ls;
    int bsel = -1;
#pragma unroll
    for (int j = 15; j >= 0; --j) {
      if (bsel < 0) {
        if (cum + (long)cnt[j] >= (long)KTAIL || j == 0) {
          bsel = j;
        } else {
          cum += (long)cnt[j];
          ab  += sm[j];
        }
      }
    }
    long r = (long)KTAIL - cum;
    double avg = cnt[bsel] ? sm[bsel] / (double)cnt[bsel] : 0.0;
    out[0] = (float)((ab + (double)r * avg) / (double)KTAIL);
  }
}

extern "C" void kernel_launch(void* const* d_in, const int* in_sizes, int n_in,
                              void* d_out, int out_size, void* d_ws, size_t ws_size,
                              hipStream_t stream) {
  (void)in_sizes; (void)n_in; (void)out_size; (void)ws_size;
  const float4* in = (const float4*)d_in[0];
  const float4* tg = (const float4*)d_in[1];
  float* out = (float*)d_out;
  char* ws = (char*)d_ws;

  unsigned* gcnt = (unsigned*)ws;                  // 16 KB
  double*   gsum = (double*)(ws + NBIN * 4);       // 32 KB

  // zero accumulators every call (graph replays reuse ws)
  hipMemsetAsync(gcnt, 0, NBIN * 4 + NBIN * 8, stream);

  k_main<<<dim3(NBLK), dim3(NTHR), 0, stream>>>(in, tg, gcnt, gsum);
  k_final<<<1, 256, 0, stream>>>(gcnt, gsum, out);
}

// Round 9
// 42.050 us; speedup vs baseline: 9.0555x; 1.0267x over previous
//
#include <hip/hip_runtime.h>

// BootstrapLoss: mean of the top-20% per-pixel (channel-mean) squared errors.
// input/target: [64, 3, 256, 256] fp32. N_pix = 4194304; k = 838861 largest.
//
// Single-pass histogram selection on the float bit pattern (non-negative
// floats order like their uint32 bit patterns). 4096 bins = sign+exp+4
// mantissa bits (bits>>19). Per-bin (count,sum) packed into ONE 64-bit LDS
// atomic per value: [63:48] count, [47:0] sum in 1/1024 fixed point
// (quant error <= 5e-4 vs tolerance 448; measured absmax 0.0).
//
// R8: packed atomic gained ~2.5us (LDS atomic pressure partially confirmed).
// R9 experiment: TWO sub-histograms split by wave parity to halve
// same-address contention on the ~150 hot bins. 64KB LDS -> 2 blocks/CU =
// 16 waves/CU (R2/R6 proved 16 vs 32 waves is BW-equivalent here).
// Pre-commit: delta < 1us => memory-path roofline (402 MB mandatory read at
// ~10.5 TB/s effective; working set >> L2), declare ROOFLINE.
//
// R4/R5 lesson: NO per-block __threadfence finalize (L2 writeback storms).

#define NPIX   (64 * 256 * 256)   // 4194304
#define NV4    (NPIX / 4)         // 1048576
#define HW     65536
#define CHW    196608
#define KTAIL  838861             // 4194304 - int(0.8 * 4194304)
#define NBIN   4096
#define NBLK   1024
#define NTHR   512
#define VITER  2                  // NBLK * NTHR * VITER == NV4

#define FIXSHIFT 10               // sum fixed point = value * 1024
#define CNTSHIFT 48
#define SUMMASK  ((1ull << CNTSHIFT) - 1ull)

__device__ inline float sqf(float x) { return x * x; }

__global__ __launch_bounds__(NTHR)
void k_main(const float4* __restrict__ in, const float4* __restrict__ tg,
            unsigned* __restrict__ gcnt, double* __restrict__ gsum) {
  __shared__ unsigned long long h[2][NBIN];   // 64 KB, wave-parity split
  for (int j = threadIdx.x; j < NBIN; j += NTHR) { h[0][j] = 0ull; h[1][j] = 0ull; }
  __syncthreads();

  const int par = (threadIdx.x >> 6) & 1;     // wave parity
  const float S = 65025.0f / 3.0f;            // (255^2)/3
#pragma unroll
  for (int u = 0; u < VITER; ++u) {
    const int i  = (blockIdx.x * VITER + u) * NTHR + threadIdx.x;  // vec4 idx
    const int p  = i << 2;
    const int bb = p >> 16;           // batch (p / HW)
    const int hw = p & (HW - 1);
    const int base4 = (bb * CHW + hw) >> 2;
    float4 a0 = in[base4];
    float4 a1 = in[base4 + HW / 4];
    float4 a2 = in[base4 + HW / 2];
    float4 t0 = tg[base4];
    float4 t1 = tg[base4 + HW / 4];
    float4 t2 = tg[base4 + HW / 2];
    float vv[4];
    vv[0] = (sqf(a0.x - t0.x) + sqf(a1.x - t1.x) + sqf(a2.x - t2.x)) * S;
    vv[1] = (sqf(a0.y - t0.y) + sqf(a1.y - t1.y) + sqf(a2.y - t2.y)) * S;
    vv[2] = (sqf(a0.z - t0.z) + sqf(a1.z - t1.z) + sqf(a2.z - t2.z)) * S;
    vv[3] = (sqf(a0.w - t0.w) + sqf(a1.w - t1.w) + sqf(a2.w - t2.w)) * S;
#pragma unroll
    for (int c = 0; c < 4; ++c) {
      unsigned bin = __float_as_uint(vv[c]) >> 19;
      unsigned long long q =
          (unsigned long long)(vv[c] * (float)(1 << FIXSHIFT) + 0.5f);
      atomicAdd(&h[par][bin], (1ull << CNTSHIFT) | q);
    }
  }
  __syncthreads();

  // flush block-private histogram to global accumulators (merge both packed
  // copies with a plain add: count <= 4096 fits 16b, sum < 2^48, no carry)
  for (int j = threadIdx.x; j < NBIN; j += NTHR) {
    unsigned long long v = h[0][j] + h[1][j];
    if (v) {
      unsigned c = (unsigned)(v >> CNTSHIFT);
      double s = (double)(v & SUMMASK) * (1.0 / (double)(1 << FIXSHIFT));
      atomicAdd(&gcnt[j], c);
      atomicAdd(&gsum[j], s);
    }
  }
}

// 256 threads; t owns bins [16t, 16t+16). Hillis-Steele suffix scan over the
// 256 chunk totals (count + sum), then the unique chunk containing the k-th
// largest resolves its 16 bins from registers (static-index unrolled).
__global__ __launch_bounds__(256)
void k_final(const unsigned* __restrict__ gcnt,
             const double* __restrict__ gsum,
             float* __restrict__ out) {
  __shared__ unsigned cumC[256];
  __shared__ double   cumS[256];
  const int t = threadIdx.x;

  unsigned cnt[16];
  double   sm[16];
  unsigned lc = 0u;
  double   ls = 0.0;
#pragma unroll
  for (int j = 0; j < 16; ++j) {
    int idx = t * 16 + j;
    cnt[j] = gcnt[idx];
    sm[j]  = gsum[idx];
    lc += cnt[j];
    ls += sm[j];
  }
  cumC[t] = lc;
  cumS[t] = ls;
  __syncthreads();

  // inclusive suffix scan: cumC[t] = sum_{t' >= t} chunk_count(t')
#pragma unroll
  for (int off = 1; off < 256; off <<= 1) {
    unsigned c = (t + off < 256) ? cumC[t + off] : 0u;
    double   s = (t + off < 256) ? cumS[t + off] : 0.0;
    __syncthreads();
    cumC[t] += c;
    cumS[t] += s;
    __syncthreads();
  }

  const unsigned above = cumC[t] - lc;   // count in chunks strictly above t
  if (above < (unsigned)KTAIL && cumC[t] >= (unsigned)KTAIL) {
    long   cum = (long)above;
    double ab  = cumS[t] - ls;
    int bsel = -1;
#pragma unroll
    for (int j = 15; j >= 0; --j) {
      if (bsel < 0) {
        if (cum + (long)cnt[j] >= (long)KTAIL || j == 0) {
          bsel = j;
        } else {
          cum += (long)cnt[j];
          ab  += sm[j];
        }
      }
    }
    long r = (long)KTAIL - cum;
    double avg = cnt[bsel] ? sm[bsel] / (double)cnt[bsel] : 0.0;
    out[0] = (float)((ab + (double)r * avg) / (double)KTAIL);
  }
}

extern "C" void kernel_launch(void* const* d_in, const int* in_sizes, int n_in,
                              void* d_out, int out_size, void* d_ws, size_t ws_size,
                              hipStream_t stream) {
  (void)in_sizes; (void)n_in; (void)out_size; (void)ws_size;
  const float4* in = (const float4*)d_in[0];
  const float4* tg = (const float4*)d_in[1];
  float* out = (float*)d_out;
  char* ws = (char*)d_ws;

  unsigned* gcnt = (unsigned*)ws;                  // 16 KB
  double*   gsum = (double*)(ws + NBIN * 4);       // 32 KB

  // zero accumulators every call (graph replays reuse ws)
  hipMemsetAsync(gcnt, 0, NBIN * 4 + NBIN * 8, stream);

  k_main<<<dim3(NBLK), dim3(NTHR), 0, stream>>>(in, tg, gcnt, gsum);
  k_final<<<1, 256, 0, stream>>>(gcnt, gsum, out);
}

// Round 10
// 36.428 us; speedup vs baseline: 10.4529x; 1.1543x over previous
//
#include <hip/hip_runtime.h>

// BootstrapLoss: mean of the top-20% per-pixel (channel-mean) squared errors.
// input/target: [64, 3, 256, 256] fp32. N_pix = 4194304; k = 838861 largest.
//
// Single-pass histogram selection on the float bit pattern (non-negative
// floats order like their uint32 bit patterns). 4096 bins = sign+exp+4
// mantissa bits (bits>>19). LDS: per-bin (count,sum) packed in ONE u64
// ([63:48] count | [47:0] sum in 1/1024 fixed point), 2 copies split by
// wave parity (halves hot-bin contention). GLOBAL: one u64 per bin,
// [63:40] count | [39:0] sum in units of 1.0 (count<=4.2M<2^24; tail sum
// ~1.9e10 < 2^40; per-flush rounding <=0.5 -> total error <=256 per bin,
// <<0.1 on the mean; measured absmax 0.0 at FIX10 LDS).
//
// Perf model: k_main reads 402 MB once at ~10.9 TB/s effective (mostly
// L3-resident, FETCH ~49MB) — consistent with the XCD<->IC fabric ceiling
// (~1.35 TB/s/XCD); occupancy x2 and ILP restructure both null. Tail levers
// this round: 512 blocks (halves flush chains), packed global u64 (halves
// flush atomics, 32KB memset).
//
// R4/R5 lesson: NO per-block __threadfence finalize (L2 writeback storms).

#define NPIX   (64 * 256 * 256)   // 4194304
#define NV4    (NPIX / 4)         // 1048576
#define HW     65536
#define CHW    196608
#define KTAIL  838861             // 4194304 - int(0.8 * 4194304)
#define NBIN   4096
#define NBLK   512
#define NTHR   512
#define VITER  4                  // NBLK * NTHR * VITER == NV4

#define FIXSHIFT 10               // LDS sum fixed point = value * 1024
#define CNTSHIFT 48               // LDS pack
#define SUMMASK  ((1ull << CNTSHIFT) - 1ull)
#define GCNTSHIFT 40              // global pack: [63:40] cnt | [39:0] sum (1.0)
#define GSUMMASK  ((1ull << GCNTSHIFT) - 1ull)

__device__ inline float sqf(float x) { return x * x; }

__global__ __launch_bounds__(NTHR)
void k_main(const float4* __restrict__ in, const float4* __restrict__ tg,
            unsigned long long* __restrict__ gpack) {
  __shared__ unsigned long long h[2][NBIN];   // 64 KB, wave-parity split
  for (int j = threadIdx.x; j < NBIN; j += NTHR) { h[0][j] = 0ull; h[1][j] = 0ull; }
  __syncthreads();

  const int par = (threadIdx.x >> 6) & 1;     // wave parity
  const float S = 65025.0f / 3.0f;            // (255^2)/3
#pragma unroll
  for (int u = 0; u < VITER; ++u) {
    const int i  = (blockIdx.x * VITER + u) * NTHR + threadIdx.x;  // vec4 idx
    const int p  = i << 2;
    const int bb = p >> 16;           // batch (p / HW)
    const int hw = p & (HW - 1);
    const int base4 = (bb * CHW + hw) >> 2;
    float4 a0 = in[base4];
    float4 a1 = in[base4 + HW / 4];
    float4 a2 = in[base4 + HW / 2];
    float4 t0 = tg[base4];
    float4 t1 = tg[base4 + HW / 4];
    float4 t2 = tg[base4 + HW / 2];
    float vv[4];
    vv[0] = (sqf(a0.x - t0.x) + sqf(a1.x - t1.x) + sqf(a2.x - t2.x)) * S;
    vv[1] = (sqf(a0.y - t0.y) + sqf(a1.y - t1.y) + sqf(a2.y - t2.y)) * S;
    vv[2] = (sqf(a0.z - t0.z) + sqf(a1.z - t1.z) + sqf(a2.z - t2.z)) * S;
    vv[3] = (sqf(a0.w - t0.w) + sqf(a1.w - t1.w) + sqf(a2.w - t2.w)) * S;
#pragma unroll
    for (int c = 0; c < 4; ++c) {
      unsigned bin = __float_as_uint(vv[c]) >> 19;
      unsigned long long q =
          (unsigned long long)(vv[c] * (float)(1 << FIXSHIFT) + 0.5f);
      atomicAdd(&h[par][bin], (1ull << CNTSHIFT) | q);
    }
  }
  __syncthreads();

  // flush: merge parity copies (no carry: cnt<=4096 in 16b, sum<2^48) and
  // repack to global layout with ONE u64 atomic per nonzero bin.
  for (int j = threadIdx.x; j < NBIN; j += NTHR) {
    unsigned long long v = h[0][j] + h[1][j];
    if (v) {
      unsigned long long c = v >> CNTSHIFT;
      // round LDS fixed-point (x1024) to integer units of 1.0
      unsigned long long s =
          ((v & SUMMASK) + (1ull << (FIXSHIFT - 1))) >> FIXSHIFT;
      atomicAdd(&gpack[j], (c << GCNTSHIFT) | s);
    }
  }
}

// 256 threads; t owns bins [16t, 16t+16). Hillis-Steele suffix scan over the
// 256 chunk totals (count + sum), then the unique chunk containing the k-th
// largest resolves its 16 bins from registers (static-index unrolled).
__global__ __launch_bounds__(256)
void k_final(const unsigned long long* __restrict__ gpack,
             float* __restrict__ out) {
  __shared__ unsigned cumC[256];
  __shared__ double   cumS[256];
  const int t = threadIdx.x;

  unsigned cnt[16];
  double   sm[16];
  unsigned lc = 0u;
  double   ls = 0.0;
#pragma unroll
  for (int j = 0; j < 16; ++j) {
    unsigned long long v = gpack[t * 16 + j];
    cnt[j] = (unsigned)(v >> GCNTSHIFT);
    sm[j]  = (double)(v & GSUMMASK);
    lc += cnt[j];
    ls += sm[j];
  }
  cumC[t] = lc;
  cumS[t] = ls;
  __syncthreads();

  // inclusive suffix scan: cumC[t] = sum_{t' >= t} chunk_count(t')
#pragma unroll
  for (int off = 1; off < 256; off <<= 1) {
    unsigned c = (t + off < 256) ? cumC[t + off] : 0u;
    double   s = (t + off < 256) ? cumS[t + off] : 0.0;
    __syncthreads();
    cumC[t] += c;
    cumS[t] += s;
    __syncthreads();
  }

  const unsigned above = cumC[t] - lc;   // count in chunks strictly above t
  if (above < (unsigned)KTAIL && cumC[t] >= (unsigned)KTAIL) {
    long   cum = (long)above;
    double ab  = cumS[t] - ls;
    int bsel = -1;
#pragma unroll
    for (int j = 15; j >= 0; --j) {
      if (bsel < 0) {
        if (cum + (long)cnt[j] >= (long)KTAIL || j == 0) {
          bsel = j;
        } else {
          cum += (long)cnt[j];
          ab  += sm[j];
        }
      }
    }
    long r = (long)KTAIL - cum;
    double avg = cnt[bsel] ? sm[bsel] / (double)cnt[bsel] : 0.0;
    out[0] = (float)((ab + (double)r * avg) / (double)KTAIL);
  }
}

extern "C" void kernel_launch(void* const* d_in, const int* in_sizes, int n_in,
                              void* d_out, int out_size, void* d_ws, size_t ws_size,
                              hipStream_t stream) {
  (void)in_sizes; (void)n_in; (void)out_size; (void)ws_size;
  const float4* in = (const float4*)d_in[0];
  const float4* tg = (const float4*)d_in[1];
  float* out = (float*)d_out;

  unsigned long long* gpack = (unsigned long long*)d_ws;   // 32 KB

  // zero accumulators every call (graph replays reuse ws)
  hipMemsetAsync(gpack, 0, NBIN * 8, stream);

  k_main<<<dim3(NBLK), dim3(NTHR), 0, stream>>>(in, tg, gpack);
  k_final<<<1, 256, 0, stream>>>(gpack, out);
}